// Round 2
// 876.718 us; speedup vs baseline: 1.4461x; 1.4461x over previous
//
#include <hip/hip_runtime.h>
#include <hip/hip_bf16.h>
#include <math.h>

// STAttentionBlock  N=32 C=64 T=400 V=27 S=2 IC=16 — f32 I/O, f32 compute.
// Round 5: pixel-parallel SGPR-weight GEMM stages (round-4 residual bug fixed).
//   k_stage1: attention-apply + conv_outs+BN+res+leaky + conv_ff+BN+res+leaky
//             fused. Lane = pixel. Weights via uniform s_load. mm AND y1 kept
//             entirely in registers; xs tile stays = x so both residuals use x.
//   k_stage2: temporal 3x1 conv with t-halo tile, same SGPR-weight scheme.
//   BN folded into transposed weights by k_prep.

typedef __hip_bfloat16 bf16;

#define NN 32
#define CH 64
#define TT 400
#define VV 27
#define PIX 10800            // T*V
#define NSUV (32*2*27*27)    // 46656
#define XTOT (NN*CH*PIX)     // 22118400

#define TB1 9                // t per block, stage1
#define PXS1 (TB1*27)        // 243 active pixel lanes
#define NT1 45               // ceil(400/9)
#define TB2 9                // t per block, stage2
#define PXS2 (TB2*27)
#define NT2 45

__device__ __forceinline__ float lrelu(float x) { return x >= 0.f ? x : 0.1f * x; }
__device__ __forceinline__ float4 ld4(const float* p) { return *reinterpret_cast<const float4*>(p); }
__device__ __forceinline__ void st4(float* p, float4 v) { *reinterpret_cast<float4*>(p) = v; }
#define FMA4(A, S, V) { (A).x += (S)*(V).x; (A).y += (S)*(V).y; (A).z += (S)*(V).z; (A).w += (S)*(V).w; }

__device__ __forceinline__ void st_y(float* p, float v) { *p = v; }
__device__ __forceinline__ void st_y(bf16* p, float v) { *p = __float2bfloat16(v); }
__device__ __forceinline__ float ld_y(const float* p) { return *p; }
__device__ __forceinline__ float ld_y(const bf16* p) { return __bfloat162float(*p); }

// ---------------------------------------------------------------------------
// k_prep: BN-folded, transposed weights.
//   wfoT[j*64+o] = w_outs[o][j]*inv_o   (j = s*64+c, K=128)
//   wffT[c*64+o] = w_ff[o][c]*inv_f
//   wtT [k*64+o] = w_t[o][k]*inv_t      (k = c*3+kt, K=192)
//   bf*[o] = b[o]*inv + beta
// ---------------------------------------------------------------------------
__global__ void k_prep(
    const float* __restrict__ w_outs, const float* __restrict__ b_outs,
    const float* __restrict__ go, const float* __restrict__ bo,
    const float* __restrict__ mo, const float* __restrict__ vo,
    const float* __restrict__ w_ff, const float* __restrict__ b_ff,
    const float* __restrict__ gf, const float* __restrict__ bf,
    const float* __restrict__ mf, const float* __restrict__ vf,
    const float* __restrict__ w_t, const float* __restrict__ b_t,
    const float* __restrict__ gt, const float* __restrict__ btb,
    const float* __restrict__ mt, const float* __restrict__ vt,
    float* __restrict__ wfoT, float* __restrict__ bfo,
    float* __restrict__ wffT, float* __restrict__ bff,
    float* __restrict__ wtT, float* __restrict__ bft)
{
    const int total = 8192 + 4096 + 12288 + 192;
    for (int idx = blockIdx.x * 256 + threadIdx.x; idx < total; idx += gridDim.x * 256) {
        if (idx < 8192) {
            int o = idx & 63, j = idx >> 6;
            float inv = go[o] * rsqrtf(vo[o] + 1e-5f);
            wfoT[idx] = w_outs[o * 128 + j] * inv;
        } else if (idx < 12288) {
            int r = idx - 8192; int o = r & 63, c = r >> 6;
            float inv = gf[o] * rsqrtf(vf[o] + 1e-5f);
            wffT[r] = w_ff[o * 64 + c] * inv;
        } else if (idx < 24576) {
            int r = idx - 12288; int o = r & 63, k = r >> 6;
            float inv = gt[o] * rsqrtf(vt[o] + 1e-5f);
            wtT[r] = w_t[o * 192 + k] * inv;
        } else {
            int r = idx - 24576; int o = r & 63, which = r >> 6;
            if (which == 0) {
                float inv = go[o] * rsqrtf(vo[o] + 1e-5f);
                bfo[o] = b_outs[o] * inv + bo[o] - mo[o] * inv;
            } else if (which == 1) {
                float inv = gf[o] * rsqrtf(vf[o] + 1e-5f);
                bff[o] = b_ff[o] * inv + bf[o] - mf[o] * inv;
            } else {
                float inv = gt[o] * rsqrtf(vt[o] + 1e-5f);
                bft[o] = b_t[o] * inv + btb[o] - mt[o] * inv;
            }
        }
    }
}

// ---------------------------------------------------------------------------
// k_pbias: pb[s][qk][c][u] = b_in + sum_cc w_in * pe[cc][u]  (PE absorbed)
// ---------------------------------------------------------------------------
__global__ __launch_bounds__(256) void k_pbias(
    const float* __restrict__ w_in, const float* __restrict__ b_in,
    float* __restrict__ pb)
{
    __shared__ float pe[64 * 27];
    const int tid = threadIdx.x;
    for (int idx = tid; idx < 1728; idx += 256) {
        int c = idx / 27, u = idx % 27;
        float div = expf(-0.28782313662425575f * (float)(c >> 1));
        float ang = div * (float)u;
        pe[idx] = (c & 1) ? cosf(ang) : sinf(ang);
    }
    __syncthreads();
    for (int idx = tid; idx < 1792; idx += 256) {
        int u = idx % 28, r = idx / 28;
        int c = r % 16, sq = r / 16;
        if (u >= 27) { pb[idx] = 0.f; continue; }
        int s = sq >> 1, qk = sq & 1;
        int row = qk * 32 + s * 16 + c;
        float acc = b_in[row];
        for (int cc = 0; cc < 64; ++cc) acc += w_in[row * 64 + cc] * pe[cc * 27 + u];
        pb[idx] = acc;
    }
}

// ---------------------------------------------------------------------------
// k_scores: grid (25 tchunks, 2 s, 32 n), unchanged from round 3.
// ---------------------------------------------------------------------------
__global__ __launch_bounds__(256) void k_scores(
    const float* __restrict__ x, const float* __restrict__ w_in,
    const float* __restrict__ pb, float* __restrict__ scores)
{
    const int tid = threadIdx.x;
    const int s = blockIdx.y, n = blockIdx.z;
    const int t0 = blockIdx.x * 16;

    __shared__ __align__(16) float wq[16 * 68], wk[16 * 68];
    __shared__ __align__(16) float pbs[2 * 16 * 28];
    __shared__ __align__(16) float xss[2 * 64 * 28];
    __shared__ __align__(16) float qkb[4 * 16 * 28];

    for (int idx = tid; idx < 1024; idx += 256) {
        int c = idx >> 6, cc = idx & 63;
        wq[c * 68 + cc] = w_in[(s * 16 + c) * 64 + cc];
        wk[c * 68 + cc] = w_in[(32 + s * 16 + c) * 64 + cc];
    }
    for (int idx = tid; idx < 896; idx += 256)
        pbs[idx] = pb[s * 896 + idx];

    const int pug = tid % 7, pcg = (tid / 7) % 8, pqk = (tid / 56) & 1, pt2 = tid / 112;
    const int su = tid / 7, svg = tid % 7;
    float4 sacc = {0.f, 0.f, 0.f, 0.f};

    for (int tp = 0; tp < 8; ++tp) {
        __syncthreads();
        for (int idx = tid; idx < 3456; idx += 256) {
            int t2 = idx / 1728, r = idx - t2 * 1728;
            int c = r / 27, u = r - c * 27;
            xss[(t2 * 64 + c) * 28 + u] = x[(n * 64 + c) * PIX + (t0 + tp * 2 + t2) * 27 + u];
        }
        __syncthreads();
        if (tid < 224) {
            const float* wsel = pqk ? wk : wq;
            const float* xb = &xss[pt2 * 64 * 28];
            const int c0 = pcg * 2, u0 = pug * 4;
            float4 a0 = {0,0,0,0}, a1 = {0,0,0,0};
            #pragma unroll
            for (int cc4 = 0; cc4 < 16; ++cc4) {
                float4 w0 = ld4(&wsel[c0 * 68 + cc4 * 4]);
                float4 w1 = ld4(&wsel[(c0 + 1) * 68 + cc4 * 4]);
                float4 xv;
                xv = ld4(&xb[(cc4 * 4 + 0) * 28 + u0]); FMA4(a0, w0.x, xv); FMA4(a1, w1.x, xv);
                xv = ld4(&xb[(cc4 * 4 + 1) * 28 + u0]); FMA4(a0, w0.y, xv); FMA4(a1, w1.y, xv);
                xv = ld4(&xb[(cc4 * 4 + 2) * 28 + u0]); FMA4(a0, w0.z, xv); FMA4(a1, w1.z, xv);
                xv = ld4(&xb[(cc4 * 4 + 3) * 28 + u0]); FMA4(a0, w0.w, xv); FMA4(a1, w1.w, xv);
            }
            float4 p0 = ld4(&pbs[(pqk * 16 + c0) * 28 + u0]);
            float4 p1 = ld4(&pbs[(pqk * 16 + c0 + 1) * 28 + u0]);
            a0.x += p0.x; a0.y += p0.y; a0.z += p0.z; a0.w += p0.w;
            a1.x += p1.x; a1.y += p1.y; a1.z += p1.z; a1.w += p1.w;
            float* qo = &qkb[((pt2 * 2 + pqk) * 16) * 28];
            st4(&qo[c0 * 28 + u0], a0);
            st4(&qo[(c0 + 1) * 28 + u0], a1);
        }
        __syncthreads();
        if (tid < 189) {
            #pragma unroll
            for (int t2 = 0; t2 < 2; ++t2) {
                const float* qb = &qkb[(t2 * 2 + 0) * 16 * 28];
                const float* kb = &qkb[(t2 * 2 + 1) * 16 * 28];
                #pragma unroll
                for (int c = 0; c < 16; ++c) {
                    float qv = qb[c * 28 + su];
                    float4 kv = ld4(&kb[c * 28 + svg * 4]);
                    FMA4(sacc, qv, kv);
                }
            }
        }
    }
    if (tid < 189) {
        float* sb = scores + (n * 2 + s) * 729 + su * 27 + svg * 4;
        if (svg * 4 + 0 < 27) atomicAdd(&sb[0], sacc.x);
        if (svg * 4 + 1 < 27) atomicAdd(&sb[1], sacc.y);
        if (svg * 4 + 2 < 27) atomicAdd(&sb[2], sacc.z);
        if (svg * 4 + 3 < 27) atomicAdd(&sb[3], sacc.w);
    }
}

// ---------------------------------------------------------------------------
// k_att: att = tanh(scores/(IC*T)) * alpha_s + att0
// ---------------------------------------------------------------------------
__global__ void k_att(const float* __restrict__ scores,
                      const float* __restrict__ alphas,
                      const float* __restrict__ att0,
                      float* __restrict__ att)
{
    int i = blockIdx.x * 256 + threadIdx.x;
    if (i >= NSUV) return;
    int r = i % 1458;
    int s = r / 729;
    att[i] = tanhf(scores[i] * (1.f / 6400.f)) * alphas[s] + att0[r];
}

// ---------------------------------------------------------------------------
// k_stage1: per (n, 9-t chunk). Lane = one pixel (tt,v).
//   mm[j] (j=s*64+c) computed per-lane in register chunks of 8 from LDS
//   (x tile + transposed att), folded into acc[64] (=y1) via SGPR weights.
//   ff stage feeds DIRECTLY from acc[] registers (per-pixel GEMM), so xs
//   stays = x and both residuals correctly use x.
// ---------------------------------------------------------------------------
template <typename YT>
__global__ __launch_bounds__(256, 2) void k_stage1(
    const float* __restrict__ x, const float* __restrict__ att,
    const float* __restrict__ wfoT, const float* __restrict__ bfo,
    const float* __restrict__ wffT, const float* __restrict__ bff,
    YT* __restrict__ y2)
{
    const int tid = threadIdx.x;
    const int n = blockIdx.y, t0 = blockIdx.x * TB1;

    __shared__ __align__(16) float alpT[2 * 27 * 28];      // [s][v][u], u padded
    __shared__ __align__(16) float xs[64 * TB1 * 28];      // [c][tt][u], u padded — stays = x

    for (int idx = tid; idx < 1458; idx += 256) {
        int s = idx / 729, r = idx - s * 729, u = r / 27, v = r - u * 27;
        alpT[(s * 27 + v) * 28 + u] = att[n * 1458 + idx];
    }
    for (int idx = tid; idx < 54; idx += 256) alpT[idx * 28 + 27] = 0.f;
    for (int idx = tid; idx < 64 * TB1 * 28; idx += 256) {
        int u = idx % 28, ct = idx / 28;
        int tt = ct % TB1, c = ct / TB1;
        int t = t0 + tt;
        xs[idx] = (u < 27 && t < TT) ? x[(n * 64 + c) * PIX + t * 27 + u] : 0.f;
    }
    __syncthreads();

    const int pcl = tid < PXS1 ? tid : PXS1 - 1;   // clamp: uniform control flow
    const int tt = pcl / 27, v = pcl - tt * 27;

    float acc[64];
    #pragma unroll
    for (int o = 0; o < 64; ++o) acc[o] = 0.f;

    const float* aT0 = &alpT[v * 28];
    for (int sc = 0; sc < 16; ++sc) {              // sc = s*8 + c8; j0 = sc*8
        const int s = sc >> 3;
        const float* ab = aT0 + s * (27 * 28);
        const float* xb = &xs[((sc & 7) * 8 * TB1 + tt) * 28];
        float mr[8];
        #pragma unroll
        for (int k = 0; k < 8; ++k) mr[k] = 0.f;
        #pragma unroll
        for (int u4 = 0; u4 < 7; ++u4) {
            float4 a4 = ld4(&ab[u4 * 4]);
            #pragma unroll
            for (int k = 0; k < 8; ++k) {
                float4 x4 = ld4(&xb[k * (TB1 * 28) + u4 * 4]);
                mr[k] += a4.x * x4.x + a4.y * x4.y + a4.z * x4.z + a4.w * x4.w;
            }
        }
        const int j0 = sc * 8;
        #pragma unroll
        for (int k = 0; k < 8; ++k) {
            const float* wr = &wfoT[(j0 + k) * 64]; // uniform -> s_load
            float m = mr[k];
            #pragma unroll
            for (int o = 0; o < 64; ++o) acc[o] += wr[o] * m;
        }
    }

    // y1 = lrelu(x + acc + bfo)  — kept in registers
    #pragma unroll
    for (int o = 0; o < 64; ++o) {
        float xr = xs[(o * TB1 + tt) * 28 + v];
        acc[o] = lrelu(xr + acc[o] + bfo[o]);
    }

    // ff stage: per-pixel GEMM from registers; residual = x (still in xs)
    const bool wr_ok = (tid < PXS1) && (t0 + tt < TT);
    YT* yb = &y2[(size_t)(n * 64) * PIX + (t0 + tt) * 27 + v];
    for (int oc = 0; oc < 4; ++oc) {
        float a2[16];
        #pragma unroll
        for (int i = 0; i < 16; ++i) a2[i] = bff[oc * 16 + i];
        #pragma unroll
        for (int c = 0; c < 64; ++c) {
            float yv = acc[c];
            const float* wr = &wffT[c * 64 + oc * 16];   // uniform -> s_load
            #pragma unroll
            for (int i = 0; i < 16; ++i) a2[i] += wr[i] * yv;
        }
        if (wr_ok) {
            #pragma unroll
            for (int i = 0; i < 16; ++i) {
                float res = xs[((oc * 16 + i) * TB1 + tt) * 28 + v];   // x residual
                st_y(&yb[(size_t)(oc * 16 + i) * PIX], lrelu(res + a2[i]));
            }
        }
    }
}

// ---------------------------------------------------------------------------
// k_stage2: temporal 3x1 conv + BN + res + leaky. Lane = one pixel.
// y2 tile with +-1 t halo in LDS; K=192 reduction with SGPR weights.
// ---------------------------------------------------------------------------
template <typename YT>
__global__ __launch_bounds__(256, 2) void k_stage2(
    const YT* __restrict__ y2in, const float* __restrict__ wtT,
    const float* __restrict__ bft, float* __restrict__ out)
{
    const int tid = threadIdx.x;
    const int n = blockIdx.y, t0 = blockIdx.x * TB2;

    __shared__ float ys[64 * (TB2 + 2) * 28];      // [c][tt(0..10) = t0-1+tt][v]

    for (int idx = tid; idx < 64 * (TB2 + 2) * 28; idx += 256) {
        int u = idx % 28, ct = idx / 28;
        int tt = ct % (TB2 + 2), c = ct / (TB2 + 2);
        int t = t0 - 1 + tt;
        ys[idx] = (u < 27 && t >= 0 && t < TT)
                    ? ld_y(&y2in[(size_t)(n * 64 + c) * PIX + t * 27 + u]) : 0.f;
    }
    __syncthreads();

    const int pcl = tid < PXS2 ? tid : PXS2 - 1;
    const int tt = pcl / 27, v = pcl - tt * 27;

    float acc[64];
    #pragma unroll
    for (int o = 0; o < 64; ++o) acc[o] = bft[o];

    for (int c = 0; c < 64; ++c) {
        #pragma unroll
        for (int kt = 0; kt < 3; ++kt) {
            float yv = ys[(c * (TB2 + 2) + tt + kt) * 28 + v];
            const float* wr = &wtT[(c * 3 + kt) * 64];   // uniform -> s_load
            #pragma unroll
            for (int o = 0; o < 64; ++o) acc[o] += wr[o] * yv;
        }
    }

    if (tid < PXS2 && t0 + tt < TT) {
        float* ob = &out[(size_t)(n * 64) * PIX + (t0 + tt) * 27 + v];
        #pragma unroll
        for (int o = 0; o < 64; ++o) {
            float res = ys[(o * (TB2 + 2) + tt + 1) * 28 + v];
            ob[(size_t)o * PIX] = lrelu(res + acc[o]);
        }
    }
}

// ---------------------------------------------------------------------------
extern "C" void kernel_launch(void* const* d_in, const int* in_sizes, int n_in,
                              void* d_out, int out_size, void* d_ws, size_t ws_size,
                              hipStream_t stream)
{
    const float* x      = (const float*)d_in[0];
    const float* w_in   = (const float*)d_in[1];
    const float* b_in   = (const float*)d_in[2];
    const float* alphas = (const float*)d_in[3];
    const float* att0   = (const float*)d_in[4];
    const float* w_outs = (const float*)d_in[5];
    const float* b_outs = (const float*)d_in[6];
    const float* bog    = (const float*)d_in[7];
    const float* bob    = (const float*)d_in[8];
    const float* bom    = (const float*)d_in[9];
    const float* bov    = (const float*)d_in[10];
    const float* w_ff   = (const float*)d_in[11];
    const float* b_ff   = (const float*)d_in[12];
    const float* bfg    = (const float*)d_in[13];
    const float* bfb    = (const float*)d_in[14];
    const float* bfm    = (const float*)d_in[15];
    const float* bfv    = (const float*)d_in[16];
    const float* w_t    = (const float*)d_in[17];
    const float* b_t    = (const float*)d_in[18];
    const float* btg    = (const float*)d_in[19];
    const float* btb    = (const float*)d_in[20];
    const float* btm    = (const float*)d_in[21];
    const float* btv    = (const float*)d_in[22];

    // ws layout: pb 1792 | scores 46656 | att 46656 | wfoT 8192 | bfo 64 |
    //            wffT 4096 | bff 64 | wtT 12288 | bft 64 | y2
    float* pbw    = (float*)d_ws;
    float* scores = pbw + 1792;
    float* att    = scores + NSUV;
    float* wfoT   = att + NSUV;
    float* bfo    = wfoT + 8192;
    float* wffT   = bfo + 64;
    float* bff    = wffT + 4096;
    float* wtT    = bff + 64;
    float* bft    = wtT + 12288;
    void*  y2     = (void*)(bft + 64);

    const size_t prefix = 1792 + 2 * (size_t)NSUV + 24768;
    const size_t need_f32 = prefix * 4 + (size_t)XTOT * 4;
    const bool y2_f32 = (ws_size >= need_f32);

    hipMemsetAsync(scores, 0, NSUV * sizeof(float), stream);

    k_prep<<<32, 256, 0, stream>>>(w_outs, b_outs, bog, bob, bom, bov,
                                   w_ff, b_ff, bfg, bfb, bfm, bfv,
                                   w_t, b_t, btg, btb, btm, btv,
                                   wfoT, bfo, wffT, bff, wtT, bft);
    k_pbias<<<1, 256, 0, stream>>>(w_in, b_in, pbw);
    k_scores<<<dim3(25, 2, NN), 256, 0, stream>>>(x, w_in, pbw, scores);
    k_att<<<(NSUV + 255) / 256, 256, 0, stream>>>(scores, alphas, att0, att);

    if (y2_f32) {
        k_stage1<float><<<dim3(NT1, NN), 256, 0, stream>>>(x, att, wfoT, bfo,
                                                           wffT, bff, (float*)y2);
        k_stage2<float><<<dim3(NT2, NN), 256, 0, stream>>>((const float*)y2, wtT,
                                                           bft, (float*)d_out);
    } else {
        k_stage1<bf16><<<dim3(NT1, NN), 256, 0, stream>>>(x, att, wfoT, bfo,
                                                          wffT, bff, (bf16*)y2);
        k_stage2<bf16><<<dim3(NT2, NN), 256, 0, stream>>>((const bf16*)y2, wtT,
                                                          bft, (float*)d_out);
    }
}

// Round 3
// 698.196 us; speedup vs baseline: 1.8158x; 1.2557x over previous
//
#include <hip/hip_runtime.h>
#include <hip/hip_bf16.h>
#include <math.h>

// STAttentionBlock  N=32 C=64 T=400 V=27 S=2 IC=16 — f32 I/O.
// Round 6: bf16-packed LDS tiles (4 blocks/CU) + v_dot2_f32_bf16 dual-MAC
// for mm / conv_outs / ff / tconv. Weights pre-packed bf16x2 (SGPR side).
//   k_stage1: att-apply + conv_outs+BN+res+leaky + ff+BN+res+leaky, fused.
//   k_stage2: temporal 3x1 conv via [t'][v][c]-transposed bf16 tile; K-pairs
//             along c are single u32 LDS loads.

typedef __hip_bfloat16 bf16;
typedef unsigned short u16t;
typedef unsigned int u32t;

#define NN 32
#define CH 64
#define TT 400
#define VV 27
#define PIX 10800            // T*V
#define NSUV (32*2*27*27)    // 46656
#define XTOT (NN*CH*PIX)     // 22118400

#define TB1 9                // t per block, stage1
#define PXS1 (TB1*27)        // 243 active pixel lanes
#define NT1 45               // ceil(400/9)
#define TB2 9
#define PXS2 (TB2*27)
#define NT2 45

__device__ __forceinline__ float lrelu(float x) { return x >= 0.f ? x : 0.1f * x; }
__device__ __forceinline__ float4 ld4(const float* p) { return *reinterpret_cast<const float4*>(p); }
__device__ __forceinline__ void st4(float* p, float4 v) { *reinterpret_cast<float4*>(p) = v; }
__device__ __forceinline__ uint4 ld4u(const u32t* p) { return *reinterpret_cast<const uint4*>(p); }
#define FMA4(A, S, V) { (A).x += (S)*(V).x; (A).y += (S)*(V).y; (A).z += (S)*(V).z; (A).w += (S)*(V).w; }

// packed bf16 helpers
__device__ __forceinline__ u16t f2bf(float f) {
    return __bfloat16_as_ushort(__float2bfloat16(f));
}
__device__ __forceinline__ u32t packbf(float lo, float hi) {
    return ((u32t)f2bf(hi) << 16) | (u32t)f2bf(lo);
}
__device__ __forceinline__ float bf2f(u16t u) {
    return __uint_as_float(((u32t)u) << 16);
}
// v_cvt_pk_bf16_f32: dst.lo = bf16(lo), dst.hi = bf16(hi)
__device__ __forceinline__ u32t cvtpk(float lo, float hi) {
    u32t r;
    asm("v_cvt_pk_bf16_f32 %0, %1, %2" : "=v"(r) : "v"(lo), "v"(hi));
    return r;
}
// c += a.lo*b.lo + a.hi*b.hi  (bf16 pairs, f32 accum)
__device__ __forceinline__ void dot2v(float& c, u32t a, u32t b) {
    asm("v_dot2_f32_bf16 %0, %1, %2, %0" : "+v"(c) : "v"(a), "v"(b));
}
__device__ __forceinline__ void dot2s(float& c, u32t a_sgpr, u32t b) {
    asm("v_dot2_f32_bf16 %0, %1, %2, %0" : "+v"(c) : "s"(a_sgpr), "v"(b));
}

// ---------------------------------------------------------------------------
// k_prep: BN-folded, transposed, bf16x2-packed weights.
//   wfopk[j2*64+o] = pack(w_outs[o][2j2], w_outs[o][2j2+1]) * inv_o   (j2<64)
//   wffpk[c2*64+o] = pack(w_ff[o][2c2],  w_ff[o][2c2+1])  * inv_f    (c2<32)
//   wt2pk[(kt*32+c2)*64+o] = pack(w_t[o][2c2][kt], w_t[o][2c2+1][kt]) * inv_t
//   b*[o] = b[o]*inv + beta
// ---------------------------------------------------------------------------
__global__ void k_prep(
    const float* __restrict__ w_outs, const float* __restrict__ b_outs,
    const float* __restrict__ go, const float* __restrict__ bo,
    const float* __restrict__ mo, const float* __restrict__ vo,
    const float* __restrict__ w_ff, const float* __restrict__ b_ff,
    const float* __restrict__ gf, const float* __restrict__ bf,
    const float* __restrict__ mf, const float* __restrict__ vf,
    const float* __restrict__ w_t, const float* __restrict__ b_t,
    const float* __restrict__ gt, const float* __restrict__ btb,
    const float* __restrict__ mt, const float* __restrict__ vt,
    u32t* __restrict__ wfopk, float* __restrict__ bfo,
    u32t* __restrict__ wffpk, float* __restrict__ bff,
    u32t* __restrict__ wt2pk, float* __restrict__ bft)
{
    const int total = 4096 + 2048 + 6144 + 192;
    for (int idx = blockIdx.x * 256 + threadIdx.x; idx < total; idx += gridDim.x * 256) {
        if (idx < 4096) {
            int o = idx & 63, j2 = idx >> 6;
            float inv = go[o] * rsqrtf(vo[o] + 1e-5f);
            wfopk[idx] = packbf(w_outs[o * 128 + 2 * j2] * inv,
                                w_outs[o * 128 + 2 * j2 + 1] * inv);
        } else if (idx < 6144) {
            int r = idx - 4096; int o = r & 63, c2 = r >> 6;
            float inv = gf[o] * rsqrtf(vf[o] + 1e-5f);
            wffpk[r] = packbf(w_ff[o * 64 + 2 * c2] * inv,
                              w_ff[o * 64 + 2 * c2 + 1] * inv);
        } else if (idx < 12288) {
            int r = idx - 6144; int o = r & 63, q = r >> 6;   // q < 96
            int kt = q >> 5, c2 = q & 31;
            float inv = gt[o] * rsqrtf(vt[o] + 1e-5f);
            wt2pk[r] = packbf(w_t[o * 192 + (2 * c2) * 3 + kt] * inv,
                              w_t[o * 192 + (2 * c2 + 1) * 3 + kt] * inv);
        } else {
            int r = idx - 12288; int o = r & 63, which = r >> 6;
            if (which == 0) {
                float inv = go[o] * rsqrtf(vo[o] + 1e-5f);
                bfo[o] = b_outs[o] * inv + bo[o] - mo[o] * inv;
            } else if (which == 1) {
                float inv = gf[o] * rsqrtf(vf[o] + 1e-5f);
                bff[o] = b_ff[o] * inv + bf[o] - mf[o] * inv;
            } else {
                float inv = gt[o] * rsqrtf(vt[o] + 1e-5f);
                bft[o] = b_t[o] * inv + btb[o] - mt[o] * inv;
            }
        }
    }
}

// ---------------------------------------------------------------------------
// k_pbias: pb[s][qk][c][u] = b_in + sum_cc w_in * pe[cc][u]  (PE absorbed)
// ---------------------------------------------------------------------------
__global__ __launch_bounds__(256) void k_pbias(
    const float* __restrict__ w_in, const float* __restrict__ b_in,
    float* __restrict__ pb)
{
    __shared__ float pe[64 * 27];
    const int tid = threadIdx.x;
    for (int idx = tid; idx < 1728; idx += 256) {
        int c = idx / 27, u = idx % 27;
        float div = expf(-0.28782313662425575f * (float)(c >> 1));
        float ang = div * (float)u;
        pe[idx] = (c & 1) ? cosf(ang) : sinf(ang);
    }
    __syncthreads();
    for (int idx = tid; idx < 1792; idx += 256) {
        int u = idx % 28, r = idx / 28;
        int c = r % 16, sq = r / 16;
        if (u >= 27) { pb[idx] = 0.f; continue; }
        int s = sq >> 1, qk = sq & 1;
        int row = qk * 32 + s * 16 + c;
        float acc = b_in[row];
        for (int cc = 0; cc < 64; ++cc) acc += w_in[row * 64 + cc] * pe[cc * 27 + u];
        pb[idx] = acc;
    }
}

// ---------------------------------------------------------------------------
// k_scores: grid (25 tchunks, 2 s, 32 n) — unchanged (next round's target).
// ---------------------------------------------------------------------------
__global__ __launch_bounds__(256) void k_scores(
    const float* __restrict__ x, const float* __restrict__ w_in,
    const float* __restrict__ pb, float* __restrict__ scores)
{
    const int tid = threadIdx.x;
    const int s = blockIdx.y, n = blockIdx.z;
    const int t0 = blockIdx.x * 16;

    __shared__ __align__(16) float wq[16 * 68], wk[16 * 68];
    __shared__ __align__(16) float pbs[2 * 16 * 28];
    __shared__ __align__(16) float xss[2 * 64 * 28];
    __shared__ __align__(16) float qkb[4 * 16 * 28];

    for (int idx = tid; idx < 1024; idx += 256) {
        int c = idx >> 6, cc = idx & 63;
        wq[c * 68 + cc] = w_in[(s * 16 + c) * 64 + cc];
        wk[c * 68 + cc] = w_in[(32 + s * 16 + c) * 64 + cc];
    }
    for (int idx = tid; idx < 896; idx += 256)
        pbs[idx] = pb[s * 896 + idx];

    const int pug = tid % 7, pcg = (tid / 7) % 8, pqk = (tid / 56) & 1, pt2 = tid / 112;
    const int su = tid / 7, svg = tid % 7;
    float4 sacc = {0.f, 0.f, 0.f, 0.f};

    for (int tp = 0; tp < 8; ++tp) {
        __syncthreads();
        for (int idx = tid; idx < 3456; idx += 256) {
            int t2 = idx / 1728, r = idx - t2 * 1728;
            int c = r / 27, u = r - c * 27;
            xss[(t2 * 64 + c) * 28 + u] = x[(n * 64 + c) * PIX + (t0 + tp * 2 + t2) * 27 + u];
        }
        __syncthreads();
        if (tid < 224) {
            const float* wsel = pqk ? wk : wq;
            const float* xb = &xss[pt2 * 64 * 28];
            const int c0 = pcg * 2, u0 = pug * 4;
            float4 a0 = {0,0,0,0}, a1 = {0,0,0,0};
            #pragma unroll
            for (int cc4 = 0; cc4 < 16; ++cc4) {
                float4 w0 = ld4(&wsel[c0 * 68 + cc4 * 4]);
                float4 w1 = ld4(&wsel[(c0 + 1) * 68 + cc4 * 4]);
                float4 xv;
                xv = ld4(&xb[(cc4 * 4 + 0) * 28 + u0]); FMA4(a0, w0.x, xv); FMA4(a1, w1.x, xv);
                xv = ld4(&xb[(cc4 * 4 + 1) * 28 + u0]); FMA4(a0, w0.y, xv); FMA4(a1, w1.y, xv);
                xv = ld4(&xb[(cc4 * 4 + 2) * 28 + u0]); FMA4(a0, w0.z, xv); FMA4(a1, w1.z, xv);
                xv = ld4(&xb[(cc4 * 4 + 3) * 28 + u0]); FMA4(a0, w0.w, xv); FMA4(a1, w1.w, xv);
            }
            float4 p0 = ld4(&pbs[(pqk * 16 + c0) * 28 + u0]);
            float4 p1 = ld4(&pbs[(pqk * 16 + c0 + 1) * 28 + u0]);
            a0.x += p0.x; a0.y += p0.y; a0.z += p0.z; a0.w += p0.w;
            a1.x += p1.x; a1.y += p1.y; a1.z += p1.z; a1.w += p1.w;
            float* qo = &qkb[((pt2 * 2 + pqk) * 16) * 28];
            st4(&qo[c0 * 28 + u0], a0);
            st4(&qo[(c0 + 1) * 28 + u0], a1);
        }
        __syncthreads();
        if (tid < 189) {
            #pragma unroll
            for (int t2 = 0; t2 < 2; ++t2) {
                const float* qb = &qkb[(t2 * 2 + 0) * 16 * 28];
                const float* kb = &qkb[(t2 * 2 + 1) * 16 * 28];
                #pragma unroll
                for (int c = 0; c < 16; ++c) {
                    float qv = qb[c * 28 + su];
                    float4 kv = ld4(&kb[c * 28 + svg * 4]);
                    FMA4(sacc, qv, kv);
                }
            }
        }
    }
    if (tid < 189) {
        float* sb = scores + (n * 2 + s) * 729 + su * 27 + svg * 4;
        if (svg * 4 + 0 < 27) atomicAdd(&sb[0], sacc.x);
        if (svg * 4 + 1 < 27) atomicAdd(&sb[1], sacc.y);
        if (svg * 4 + 2 < 27) atomicAdd(&sb[2], sacc.z);
        if (svg * 4 + 3 < 27) atomicAdd(&sb[3], sacc.w);
    }
}

// ---------------------------------------------------------------------------
// k_att: attT[((n*2+s)*27+v)*16+e] = pack_bf16( att(u=2e,v), att(u=2e+1,v) )
//        att = tanh(scores/6400)*alpha_s + att0 ; u>=27 -> 0
// ---------------------------------------------------------------------------
__global__ void k_att(const float* __restrict__ scores,
                      const float* __restrict__ alphas,
                      const float* __restrict__ att0,
                      u32t* __restrict__ attT)
{
    int i = blockIdx.x * 256 + threadIdx.x;
    if (i >= NN * 2 * 27 * 16) return;
    int e = i & 15;
    int r = i >> 4;                 // (n*2+s)*27 + v
    int v = r % 27;
    int ns = r / 27;
    int s = ns & 1;
    const float* sb = scores + ns * 729;
    const float* ab = att0 + s * 729;
    float al = alphas[s];
    int u0 = 2 * e, u1 = 2 * e + 1;
    float a0 = (u0 < 27) ? tanhf(sb[u0 * 27 + v] * (1.f / 6400.f)) * al + ab[u0 * 27 + v] : 0.f;
    float a1 = (u1 < 27) ? tanhf(sb[u1 * 27 + v] * (1.f / 6400.f)) * al + ab[u1 * 27 + v] : 0.f;
    attT[i] = packbf(a0, a1);
}

// ---------------------------------------------------------------------------
// k_stage1: per (n, 9-t chunk). Lane = one pixel (tt,v).
//   LDS: att_s u32[2*27][16] (bf16x2 pairs along u), xs u32[64*TB1][16]
//   (bf16x2 pairs along u, pad to 32 u). 40320 B -> 4 blocks/CU.
//   mm via dot2v; fold/ff via dot2s with packed SGPR weights.
// ---------------------------------------------------------------------------
__global__ __launch_bounds__(256, 4) void k_stage1(
    const float* __restrict__ x, const u32t* __restrict__ attT,
    const u32t* __restrict__ wfopk, const float* __restrict__ bfo,
    const u32t* __restrict__ wffpk, const float* __restrict__ bff,
    u16t* __restrict__ y2)
{
    const int tid = threadIdx.x;
    const int n = blockIdx.y, t0 = blockIdx.x * TB1;

    __shared__ __align__(16) u32t att_s[2 * 27 * 16];     // 3456 B
    __shared__ __align__(16) u32t xs[64 * TB1 * 16];      // 36864 B
    const u16t* xs16 = (const u16t*)xs;

    for (int idx = tid; idx < 2 * 27 * 16; idx += 256)
        att_s[idx] = attT[n * 864 + idx];
    for (int idx = tid; idx < 64 * TB1 * 32; idx += 256) {
        int u = idx & 31, ct = idx >> 5;
        int tt = ct % TB1, c = ct / TB1;
        int t = t0 + tt;
        float val = (u < 27 && t < TT) ? x[(n * 64 + c) * PIX + t * 27 + u] : 0.f;
        ((u16t*)xs)[idx] = f2bf(val);
    }
    __syncthreads();

    const int pcl = tid < PXS1 ? tid : PXS1 - 1;   // clamp: uniform control flow
    const int tt = pcl / 27, v = pcl - tt * 27;

    float acc[64];
    #pragma unroll
    for (int o = 0; o < 64; ++o) acc[o] = 0.f;

    const u32t* aT0 = att_s + v * 16;
    for (int sc = 0; sc < 16; ++sc) {              // sc = s*8 + c8
        const int s = sc >> 3;
        const u32t* ab = aT0 + s * (27 * 16);
        const u32t* xb = xs + ((sc & 7) * 8 * TB1 + tt) * 16;
        float mr[8];
        #pragma unroll
        for (int k = 0; k < 8; ++k) mr[k] = 0.f;
        #pragma unroll
        for (int u4 = 0; u4 < 4; ++u4) {
            uint4 a4 = ld4u(ab + u4 * 4);
            #pragma unroll
            for (int k = 0; k < 8; ++k) {
                uint4 x4 = ld4u(xb + k * (TB1 * 16) + u4 * 4);
                dot2v(mr[k], a4.x, x4.x);
                dot2v(mr[k], a4.y, x4.y);
                dot2v(mr[k], a4.z, x4.z);
                dot2v(mr[k], a4.w, x4.w);
            }
        }
        u32t mp[4];
        #pragma unroll
        for (int e = 0; e < 4; ++e) mp[e] = cvtpk(mr[2 * e], mr[2 * e + 1]);
        #pragma unroll
        for (int e = 0; e < 4; ++e) {
            const u32t* wr = wfopk + (sc * 4 + e) * 64;   // uniform -> s_load
            #pragma unroll
            for (int o = 0; o < 64; ++o) dot2s(acc[o], wr[o], mp[e]);
        }
    }

    // y1 = lrelu(x + acc + bfo), packed to bf16x2 pairs (kept in registers)
    #pragma unroll
    for (int o = 0; o < 64; ++o) {
        float xr = bf2f(xs16[(o * TB1 + tt) * 32 + v]);
        acc[o] = lrelu(xr + acc[o] + bfo[o]);
    }
    u32t yp[32];
    #pragma unroll
    for (int e = 0; e < 32; ++e) yp[e] = cvtpk(acc[2 * e], acc[2 * e + 1]);

    // ff stage: residual = x (still in xs)
    const bool wr_ok = (tid < PXS1) && (t0 + tt < TT);
    u16t* yb = y2 + (size_t)(n * 64) * PIX + (t0 + tt) * 27 + v;
    #pragma unroll
    for (int oc = 0; oc < 4; ++oc) {
        float a2[16];
        #pragma unroll
        for (int i = 0; i < 16; ++i) a2[i] = bff[oc * 16 + i];
        #pragma unroll 8
        for (int c2 = 0; c2 < 32; ++c2) {
            const u32t* wr = wffpk + c2 * 64 + oc * 16;   // uniform -> s_load
            #pragma unroll
            for (int i = 0; i < 16; ++i) dot2s(a2[i], wr[i], yp[c2]);
        }
        if (wr_ok) {
            #pragma unroll
            for (int i = 0; i < 16; ++i) {
                float res = bf2f(xs16[((oc * 16 + i) * TB1 + tt) * 32 + v]);
                yb[(size_t)(oc * 16 + i) * PIX] = f2bf(lrelu(res + a2[i]));
            }
        }
    }
}

// ---------------------------------------------------------------------------
// k_stage2: temporal 3x1 conv + BN + res + leaky. Lane = one pixel.
//   LDS tile TRANSPOSED: ys[t'][v][c] bf16 (c-stride 66 -> u32 pairs aligned,
//   bank-spread). K reordered [kt][c-pairs]; each pair = one u32 LDS load.
// ---------------------------------------------------------------------------
__global__ __launch_bounds__(256, 4) void k_stage2(
    const u16t* __restrict__ y2in, const u32t* __restrict__ wt2pk,
    const float* __restrict__ bft, float* __restrict__ out)
{
    const int tid = threadIdx.x;
    const int n = blockIdx.y, t0 = blockIdx.x * TB2;

    __shared__ __align__(16) u16t ys[(TB2 + 2) * 28 * 66];    // 40656 B

    for (int idx = tid; idx < 64 * (TB2 + 2) * 28; idx += 256) {
        int u = idx % 28, r = idx / 28;
        int tp = r % (TB2 + 2), c = r / (TB2 + 2);
        if (u >= 27) continue;
        int t = t0 - 1 + tp;
        ys[(tp * 28 + u) * 66 + c] = (t >= 0 && t < TT)
            ? y2in[(size_t)(n * 64 + c) * PIX + t * 27 + u] : (u16t)0;
    }
    __syncthreads();

    const int pcl = tid < PXS2 ? tid : PXS2 - 1;
    const int tt = pcl / 27, v = pcl - tt * 27;

    float acc[64];
    #pragma unroll
    for (int o = 0; o < 64; ++o) acc[o] = bft[o];

    const u32t* ysu = (const u32t*)ys;
    #pragma unroll
    for (int kt = 0; kt < 3; ++kt) {
        const u32t* yrow = ysu + ((tt + kt) * 28 + v) * 33;
        #pragma unroll 8
        for (int c2 = 0; c2 < 32; ++c2) {
            u32t yp2 = yrow[c2];
            const u32t* wr = wt2pk + (kt * 32 + c2) * 64;    // uniform -> s_load
            #pragma unroll
            for (int o = 0; o < 64; ++o) dot2s(acc[o], wr[o], yp2);
        }
    }

    if (tid < PXS2 && t0 + tt < TT) {
        float* ob = out + (size_t)(n * 64) * PIX + (t0 + tt) * 27 + v;
        #pragma unroll
        for (int o = 0; o < 64; ++o) {
            float res = bf2f(ys[((tt + 1) * 28 + v) * 66 + o]);
            ob[(size_t)o * PIX] = lrelu(res + acc[o]);
        }
    }
}

// ---------------------------------------------------------------------------
extern "C" void kernel_launch(void* const* d_in, const int* in_sizes, int n_in,
                              void* d_out, int out_size, void* d_ws, size_t ws_size,
                              hipStream_t stream)
{
    const float* x      = (const float*)d_in[0];
    const float* w_in   = (const float*)d_in[1];
    const float* b_in   = (const float*)d_in[2];
    const float* alphas = (const float*)d_in[3];
    const float* att0   = (const float*)d_in[4];
    const float* w_outs = (const float*)d_in[5];
    const float* b_outs = (const float*)d_in[6];
    const float* bog    = (const float*)d_in[7];
    const float* bob    = (const float*)d_in[8];
    const float* bom    = (const float*)d_in[9];
    const float* bov    = (const float*)d_in[10];
    const float* w_ff   = (const float*)d_in[11];
    const float* b_ff   = (const float*)d_in[12];
    const float* bfg    = (const float*)d_in[13];
    const float* bfb    = (const float*)d_in[14];
    const float* bfm    = (const float*)d_in[15];
    const float* bfv    = (const float*)d_in[16];
    const float* w_t    = (const float*)d_in[17];
    const float* b_t    = (const float*)d_in[18];
    const float* btg    = (const float*)d_in[19];
    const float* btb    = (const float*)d_in[20];
    const float* btm    = (const float*)d_in[21];
    const float* btv    = (const float*)d_in[22];

    // ws layout (f32/u32 units):
    // pb 1792 | scores 46656 | attT 27648 | wfopk 4096 | bfo 64 |
    // wffpk 2048 | bff 64 | wt2pk 6144 | bft 64 | y2 (bf16, XTOT u16)
    float* pbw    = (float*)d_ws;
    float* scores = pbw + 1792;
    u32t*  attT   = (u32t*)(scores + NSUV);
    u32t*  wfopk  = attT + 27648;
    float* bfo    = (float*)(wfopk + 4096);
    u32t*  wffpk  = (u32t*)(bfo + 64);
    float* bff    = (float*)(wffpk + 2048);
    u32t*  wt2pk  = (u32t*)(bff + 64);
    float* bft    = (float*)(wt2pk + 6144);
    u16t*  y2     = (u16t*)(bft + 64);

    hipMemsetAsync(scores, 0, NSUV * sizeof(float), stream);

    k_prep<<<32, 256, 0, stream>>>(w_outs, b_outs, bog, bob, bom, bov,
                                   w_ff, b_ff, bfg, bfb, bfm, bfv,
                                   w_t, b_t, btg, btb, btm, btv,
                                   wfopk, bfo, wffpk, bff, wt2pk, bft);
    k_pbias<<<1, 256, 0, stream>>>(w_in, b_in, pbw);
    k_scores<<<dim3(25, 2, NN), 256, 0, stream>>>(x, w_in, pbw, scores);
    k_att<<<(NN * 2 * 27 * 16 + 255) / 256, 256, 0, stream>>>(scores, alphas, att0, attT);
    k_stage1<<<dim3(NT1, NN), 256, 0, stream>>>(x, attT, wfopk, bfo, wffpk, bff, y2);
    k_stage2<<<dim3(NT2, NN), 256, 0, stream>>>(y2, wt2pk, bft, (float*)d_out);
}

// Round 4
// 607.292 us; speedup vs baseline: 2.0876x; 1.1497x over previous
//
#include <hip/hip_runtime.h>
#include <hip/hip_bf16.h>
#include <math.h>

// STAttentionBlock  N=32 C=64 T=400 V=27 S=2 IC=16 — f32 I/O.
// Round 7: (a) launch_bounds(256,3) on stage1/2 to kill AGPR accumulator
// shuttling (VGPR_Count=64 at round 6 exposed 64V+64A split); (b) k_scores
// rewritten pixel-parallel: coalesced global->reg x, SGPR packed weights,
// dot2 proj + dot2 scores, q/k exchange via 19KB LDS.

typedef __hip_bfloat16 bf16;
typedef unsigned short u16t;
typedef unsigned int u32t;

#define NN 32
#define CH 64
#define TT 400
#define VV 27
#define PIX 10800            // T*V
#define NSUV (32*2*27*27)    // 46656
#define XTOT (NN*CH*PIX)     // 22118400

#define TB1 9                // t per block, stage1
#define PXS1 (TB1*27)        // 243 active pixel lanes
#define NT1 45
#define TB2 9
#define PXS2 (TB2*27)
#define NT2 45
#define TBS 9                // t per block, scores
#define NTS 45

__device__ __forceinline__ float lrelu(float x) { return x >= 0.f ? x : 0.1f * x; }
__device__ __forceinline__ uint4 ld4u(const u32t* p) { return *reinterpret_cast<const uint4*>(p); }
__device__ __forceinline__ uint2 ld2u(const u32t* p) { return *reinterpret_cast<const uint2*>(p); }

// packed bf16 helpers
__device__ __forceinline__ u16t f2bf(float f) {
    return __bfloat16_as_ushort(__float2bfloat16(f));
}
__device__ __forceinline__ u32t packbf(float lo, float hi) {
    return ((u32t)f2bf(hi) << 16) | (u32t)f2bf(lo);
}
__device__ __forceinline__ float bf2f(u16t u) {
    return __uint_as_float(((u32t)u) << 16);
}
__device__ __forceinline__ u32t cvtpk(float lo, float hi) {
    u32t r;
    asm("v_cvt_pk_bf16_f32 %0, %1, %2" : "=v"(r) : "v"(lo), "v"(hi));
    return r;
}
// c += a.lo*b.lo + a.hi*b.hi  (bf16 pairs, f32 accum)
__device__ __forceinline__ void dot2v(float& c, u32t a, u32t b) {
    asm("v_dot2_f32_bf16 %0, %1, %2, %0" : "+v"(c) : "v"(a), "v"(b));
}
__device__ __forceinline__ void dot2s(float& c, u32t a_sgpr, u32t b) {
    asm("v_dot2_f32_bf16 %0, %1, %2, %0" : "+v"(c) : "s"(a_sgpr), "v"(b));
}

// ---------------------------------------------------------------------------
// k_prep: BN-folded, transposed, bf16x2-packed weights + packed w_in.
//   wfopk[j2*64+o]           j2<64   conv_outs (K=128 pairs)
//   wffpk[c2*64+o]           c2<32   ff        (K=64 pairs)
//   wt2pk[(kt*32+c2)*64+o]           tconv     (K=192 as 3x32 pairs)
//   wqkpk[(sq*16+c)*32+cc2]  sq=s*2+qk, row = qk*32+s*16+c
//   b*[o] = b[o]*inv + beta
// ---------------------------------------------------------------------------
__global__ void k_prep(
    const float* __restrict__ w_outs, const float* __restrict__ b_outs,
    const float* __restrict__ go, const float* __restrict__ bo,
    const float* __restrict__ mo, const float* __restrict__ vo,
    const float* __restrict__ w_ff, const float* __restrict__ b_ff,
    const float* __restrict__ gf, const float* __restrict__ bf,
    const float* __restrict__ mf, const float* __restrict__ vf,
    const float* __restrict__ w_t, const float* __restrict__ b_t,
    const float* __restrict__ gt, const float* __restrict__ btb,
    const float* __restrict__ mt, const float* __restrict__ vt,
    const float* __restrict__ w_in,
    u32t* __restrict__ wfopk, float* __restrict__ bfo,
    u32t* __restrict__ wffpk, float* __restrict__ bff,
    u32t* __restrict__ wt2pk, float* __restrict__ bft,
    u32t* __restrict__ wqkpk)
{
    const int total = 4096 + 2048 + 6144 + 192 + 2048;
    for (int idx = blockIdx.x * 256 + threadIdx.x; idx < total; idx += gridDim.x * 256) {
        if (idx < 4096) {
            int o = idx & 63, j2 = idx >> 6;
            float inv = go[o] * rsqrtf(vo[o] + 1e-5f);
            wfopk[idx] = packbf(w_outs[o * 128 + 2 * j2] * inv,
                                w_outs[o * 128 + 2 * j2 + 1] * inv);
        } else if (idx < 6144) {
            int r = idx - 4096; int o = r & 63, c2 = r >> 6;
            float inv = gf[o] * rsqrtf(vf[o] + 1e-5f);
            wffpk[r] = packbf(w_ff[o * 64 + 2 * c2] * inv,
                              w_ff[o * 64 + 2 * c2 + 1] * inv);
        } else if (idx < 12288) {
            int r = idx - 6144; int o = r & 63, q = r >> 6;   // q < 96
            int kt = q >> 5, c2 = q & 31;
            float inv = gt[o] * rsqrtf(vt[o] + 1e-5f);
            wt2pk[r] = packbf(w_t[o * 192 + (2 * c2) * 3 + kt] * inv,
                              w_t[o * 192 + (2 * c2 + 1) * 3 + kt] * inv);
        } else if (idx < 12480) {
            int r = idx - 12288; int o = r & 63, which = r >> 6;
            if (which == 0) {
                float inv = go[o] * rsqrtf(vo[o] + 1e-5f);
                bfo[o] = b_outs[o] * inv + bo[o] - mo[o] * inv;
            } else if (which == 1) {
                float inv = gf[o] * rsqrtf(vf[o] + 1e-5f);
                bff[o] = b_ff[o] * inv + bf[o] - mf[o] * inv;
            } else {
                float inv = gt[o] * rsqrtf(vt[o] + 1e-5f);
                bft[o] = b_t[o] * inv + btb[o] - mt[o] * inv;
            }
        } else {
            int i = idx - 12480;                 // i < 2048
            int cc2 = i & 31, c = (i >> 5) & 15, sq = i >> 9;
            int s = sq >> 1, qk = sq & 1;
            int row = qk * 32 + s * 16 + c;
            wqkpk[i] = packbf(w_in[row * 64 + 2 * cc2], w_in[row * 64 + 2 * cc2 + 1]);
        }
    }
}

// ---------------------------------------------------------------------------
// k_pbias: pb[s*2+qk][c][u28] = b_in + sum_cc w_in * pe[cc][u]  (PE absorbed)
// ---------------------------------------------------------------------------
__global__ __launch_bounds__(256) void k_pbias(
    const float* __restrict__ w_in, const float* __restrict__ b_in,
    float* __restrict__ pb)
{
    __shared__ float pe[64 * 27];
    const int tid = threadIdx.x;
    for (int idx = tid; idx < 1728; idx += 256) {
        int c = idx / 27, u = idx % 27;
        float div = expf(-0.28782313662425575f * (float)(c >> 1));
        float ang = div * (float)u;
        pe[idx] = (c & 1) ? cosf(ang) : sinf(ang);
    }
    __syncthreads();
    for (int idx = tid; idx < 1792; idx += 256) {
        int u = idx % 28, r = idx / 28;
        int c = r % 16, sq = r / 16;
        if (u >= 27) { pb[idx] = 0.f; continue; }
        int s = sq >> 1, qk = sq & 1;
        int row = qk * 32 + s * 16 + c;
        float acc = b_in[row];
        for (int cc = 0; cc < 64; ++cc) acc += w_in[row * 64 + cc] * pe[cc * 27 + u];
        pb[idx] = acc;
    }
}

// ---------------------------------------------------------------------------
// k_scores: grid (45 tchunks, 2 s, 32 n). Lane = pixel (tt,u).
//   x channels: 64 coalesced global loads -> 32 bf16x2 regs (no x LDS).
//   proj: q[16],k[16] = pb + dot2s(wqkpk, xp). Exchange via LDS (stride 10),
//   score stage: lane=(ug,vg) computes 3 v's, 216 dot2v, 3 atomics.
// ---------------------------------------------------------------------------
__global__ __launch_bounds__(256, 4) void k_scores(
    const float* __restrict__ x, const u32t* __restrict__ wqkpk,
    const float* __restrict__ pb, float* __restrict__ scores)
{
    const int tid = threadIdx.x;
    const int s = blockIdx.y, n = blockIdx.z;
    const int t0 = blockIdx.x * TBS;

    __shared__ u32t qlds[TBS * 27 * 10];
    __shared__ u32t klds[TBS * 27 * 10];

    const int pcl = tid < 243 ? tid : 242;
    const int tt = pcl / 27, u = pcl - tt * 27;
    const int t = t0 + tt;
    const bool valid = (tid < 243) && (t < TT);

    // ---- load + pack x channels for this pixel ----
    u32t xp[32];
    const float* xb = x + (size_t)n * 64 * PIX + (size_t)(t < TT ? t : 0) * 27 + u;
    #pragma unroll
    for (int c2 = 0; c2 < 32; ++c2) {
        float v0 = xb[(size_t)(2 * c2) * PIX];
        float v1 = xb[(size_t)(2 * c2 + 1) * PIX];
        xp[c2] = cvtpk(v0, v1);
    }

    // ---- proj ----
    const float* pbq = pb + ((s * 2 + 0) * 16) * 28 + u;
    const float* pbk = pb + ((s * 2 + 1) * 16) * 28 + u;
    const u32t* wq = wqkpk + (s * 2 + 0) * 16 * 32;
    const u32t* wk = wqkpk + (s * 2 + 1) * 16 * 32;
    float qr[16], kr[16];
    #pragma unroll
    for (int c = 0; c < 16; ++c) { qr[c] = pbq[c * 28]; kr[c] = pbk[c * 28]; }
    #pragma unroll
    for (int c = 0; c < 16; ++c) {
        const u32t* wr = wq + c * 32;
        #pragma unroll
        for (int c2 = 0; c2 < 32; ++c2) dot2s(qr[c], wr[c2], xp[c2]);
    }
    #pragma unroll
    for (int c = 0; c < 16; ++c) {
        const u32t* wr = wk + c * 32;
        #pragma unroll
        for (int c2 = 0; c2 < 32; ++c2) dot2s(kr[c], wr[c2], xp[c2]);
    }

    if (tid < 243) {
        #pragma unroll
        for (int c2 = 0; c2 < 8; ++c2) {
            qlds[(tt * 27 + u) * 10 + c2] = valid ? cvtpk(qr[2 * c2], qr[2 * c2 + 1]) : 0u;
            klds[(tt * 27 + u) * 10 + c2] = valid ? cvtpk(kr[2 * c2], kr[2 * c2 + 1]) : 0u;
        }
    }
    __syncthreads();

    // ---- score stage ----
    const int sid = tid < 243 ? tid : 242;
    const int ug = sid / 9, vg = sid % 9;
    const int v0 = vg * 3;
    float sc0 = 0.f, sc1 = 0.f, sc2 = 0.f;
    for (int t2 = 0; t2 < TBS; ++t2) {
        const u32t* qrow = qlds + (t2 * 27 + ug) * 10;
        const u32t* k0 = klds + (t2 * 27 + v0) * 10;
        #pragma unroll
        for (int c4 = 0; c4 < 4; ++c4) {
            uint2 qp = ld2u(qrow + c4 * 2);
            uint2 ka = ld2u(k0 + c4 * 2);
            uint2 kb = ld2u(k0 + 10 + c4 * 2);
            uint2 kc = ld2u(k0 + 20 + c4 * 2);
            dot2v(sc0, qp.x, ka.x); dot2v(sc0, qp.y, ka.y);
            dot2v(sc1, qp.x, kb.x); dot2v(sc1, qp.y, kb.y);
            dot2v(sc2, qp.x, kc.x); dot2v(sc2, qp.y, kc.y);
        }
    }
    if (tid < 243) {
        float* sb = scores + (n * 2 + s) * 729 + ug * 27 + v0;
        atomicAdd(&sb[0], sc0);
        atomicAdd(&sb[1], sc1);
        atomicAdd(&sb[2], sc2);
    }
}

// ---------------------------------------------------------------------------
// k_att: attT[((n*2+s)*27+v)*16+e] = pack_bf16( att(u=2e,v), att(u=2e+1,v) )
// ---------------------------------------------------------------------------
__global__ void k_att(const float* __restrict__ scores,
                      const float* __restrict__ alphas,
                      const float* __restrict__ att0,
                      u32t* __restrict__ attT)
{
    int i = blockIdx.x * 256 + threadIdx.x;
    if (i >= NN * 2 * 27 * 16) return;
    int e = i & 15;
    int r = i >> 4;                 // (n*2+s)*27 + v
    int v = r % 27;
    int ns = r / 27;
    int s = ns & 1;
    const float* sb = scores + ns * 729;
    const float* ab = att0 + s * 729;
    float al = alphas[s];
    int u0 = 2 * e, u1 = 2 * e + 1;
    float a0 = (u0 < 27) ? tanhf(sb[u0 * 27 + v] * (1.f / 6400.f)) * al + ab[u0 * 27 + v] : 0.f;
    float a1 = (u1 < 27) ? tanhf(sb[u1 * 27 + v] * (1.f / 6400.f)) * al + ab[u1 * 27 + v] : 0.f;
    attT[i] = packbf(a0, a1);
}

// ---------------------------------------------------------------------------
// k_stage1: per (n, 9-t chunk). Lane = one pixel (tt,v).
// launch_bounds(256,3): 170-VGPR budget keeps acc[64]/yp[32] out of AGPRs.
// ---------------------------------------------------------------------------
__global__ __launch_bounds__(256, 3) void k_stage1(
    const float* __restrict__ x, const u32t* __restrict__ attT,
    const u32t* __restrict__ wfopk, const float* __restrict__ bfo,
    const u32t* __restrict__ wffpk, const float* __restrict__ bff,
    u16t* __restrict__ y2)
{
    const int tid = threadIdx.x;
    const int n = blockIdx.y, t0 = blockIdx.x * TB1;

    __shared__ __align__(16) u32t att_s[2 * 27 * 16];     // 3456 B
    __shared__ __align__(16) u32t xs[64 * TB1 * 16];      // 36864 B
    const u16t* xs16 = (const u16t*)xs;

    for (int idx = tid; idx < 2 * 27 * 16; idx += 256)
        att_s[idx] = attT[n * 864 + idx];
    for (int idx = tid; idx < 64 * TB1 * 32; idx += 256) {
        int u = idx & 31, ct = idx >> 5;
        int tt = ct % TB1, c = ct / TB1;
        int t = t0 + tt;
        float val = (u < 27 && t < TT) ? x[(n * 64 + c) * PIX + t * 27 + u] : 0.f;
        ((u16t*)xs)[idx] = f2bf(val);
    }
    __syncthreads();

    const int pcl = tid < PXS1 ? tid : PXS1 - 1;   // clamp: uniform control flow
    const int tt = pcl / 27, v = pcl - tt * 27;

    float acc[64];
    #pragma unroll
    for (int o = 0; o < 64; ++o) acc[o] = 0.f;

    const u32t* aT0 = att_s + v * 16;
    for (int sc = 0; sc < 16; ++sc) {              // sc = s*8 + c8
        const int s = sc >> 3;
        const u32t* ab = aT0 + s * (27 * 16);
        const u32t* xb = xs + ((sc & 7) * 8 * TB1 + tt) * 16;
        float mr[8];
        #pragma unroll
        for (int k = 0; k < 8; ++k) mr[k] = 0.f;
        #pragma unroll
        for (int u4 = 0; u4 < 4; ++u4) {
            uint4 a4 = ld4u(ab + u4 * 4);
            #pragma unroll
            for (int k = 0; k < 8; ++k) {
                uint4 x4 = ld4u(xb + k * (TB1 * 16) + u4 * 4);
                dot2v(mr[k], a4.x, x4.x);
                dot2v(mr[k], a4.y, x4.y);
                dot2v(mr[k], a4.z, x4.z);
                dot2v(mr[k], a4.w, x4.w);
            }
        }
        u32t mp[4];
        #pragma unroll
        for (int e = 0; e < 4; ++e) mp[e] = cvtpk(mr[2 * e], mr[2 * e + 1]);
        #pragma unroll
        for (int e = 0; e < 4; ++e) {
            const u32t* wr = wfopk + (sc * 4 + e) * 64;   // uniform -> s_load
            #pragma unroll
            for (int o = 0; o < 64; ++o) dot2s(acc[o], wr[o], mp[e]);
        }
    }

    // y1 = lrelu(x + acc + bfo), packed to bf16x2 pairs (kept in registers)
    #pragma unroll
    for (int o = 0; o < 64; ++o) {
        float xr = bf2f(xs16[(o * TB1 + tt) * 32 + v]);
        acc[o] = lrelu(xr + acc[o] + bfo[o]);
    }
    u32t yp[32];
    #pragma unroll
    for (int e = 0; e < 32; ++e) yp[e] = cvtpk(acc[2 * e], acc[2 * e + 1]);

    // ff stage: residual = x (still in xs)
    const bool wr_ok = (tid < PXS1) && (t0 + tt < TT);
    u16t* yb = y2 + (size_t)(n * 64) * PIX + (t0 + tt) * 27 + v;
    #pragma unroll
    for (int oc = 0; oc < 4; ++oc) {
        float a2[16];
        #pragma unroll
        for (int i = 0; i < 16; ++i) a2[i] = bff[oc * 16 + i];
        #pragma unroll 8
        for (int c2 = 0; c2 < 32; ++c2) {
            const u32t* wr = wffpk + c2 * 64 + oc * 16;   // uniform -> s_load
            #pragma unroll
            for (int i = 0; i < 16; ++i) dot2s(a2[i], wr[i], yp[c2]);
        }
        if (wr_ok) {
            #pragma unroll
            for (int i = 0; i < 16; ++i) {
                float res = bf2f(xs16[((oc * 16 + i) * TB1 + tt) * 32 + v]);
                yb[(size_t)(oc * 16 + i) * PIX] = f2bf(lrelu(res + a2[i]));
            }
        }
    }
}

// ---------------------------------------------------------------------------
// k_stage2: temporal 3x1 conv + BN + res + leaky. Lane = one pixel.
// launch_bounds(256,3): same AGPR fix as stage1.
// ---------------------------------------------------------------------------
__global__ __launch_bounds__(256, 3) void k_stage2(
    const u16t* __restrict__ y2in, const u32t* __restrict__ wt2pk,
    const float* __restrict__ bft, float* __restrict__ out)
{
    const int tid = threadIdx.x;
    const int n = blockIdx.y, t0 = blockIdx.x * TB2;

    __shared__ __align__(16) u16t ys[(TB2 + 2) * 28 * 66];    // 40656 B

    for (int idx = tid; idx < 64 * (TB2 + 2) * 28; idx += 256) {
        int u = idx % 28, r = idx / 28;
        int tp = r % (TB2 + 2), c = r / (TB2 + 2);
        if (u >= 27) continue;
        int t = t0 - 1 + tp;
        ys[(tp * 28 + u) * 66 + c] = (t >= 0 && t < TT)
            ? y2in[(size_t)(n * 64 + c) * PIX + t * 27 + u] : (u16t)0;
    }
    __syncthreads();

    const int pcl = tid < PXS2 ? tid : PXS2 - 1;
    const int tt = pcl / 27, v = pcl - tt * 27;

    float acc[64];
    #pragma unroll
    for (int o = 0; o < 64; ++o) acc[o] = bft[o];

    const u32t* ysu = (const u32t*)ys;
    #pragma unroll
    for (int kt = 0; kt < 3; ++kt) {
        const u32t* yrow = ysu + ((tt + kt) * 28 + v) * 33;
        #pragma unroll 8
        for (int c2 = 0; c2 < 32; ++c2) {
            u32t yp2 = yrow[c2];
            const u32t* wr = wt2pk + (kt * 32 + c2) * 64;    // uniform -> s_load
            #pragma unroll
            for (int o = 0; o < 64; ++o) dot2s(acc[o], wr[o], yp2);
        }
    }

    if (tid < PXS2 && t0 + tt < TT) {
        float* ob = out + (size_t)(n * 64) * PIX + (t0 + tt) * 27 + v;
        #pragma unroll
        for (int o = 0; o < 64; ++o) {
            float res = bf2f(ys[((tt + 1) * 28 + v) * 66 + o]);
            ob[(size_t)o * PIX] = lrelu(res + acc[o]);
        }
    }
}

// ---------------------------------------------------------------------------
extern "C" void kernel_launch(void* const* d_in, const int* in_sizes, int n_in,
                              void* d_out, int out_size, void* d_ws, size_t ws_size,
                              hipStream_t stream)
{
    const float* x      = (const float*)d_in[0];
    const float* w_in   = (const float*)d_in[1];
    const float* b_in   = (const float*)d_in[2];
    const float* alphas = (const float*)d_in[3];
    const float* att0   = (const float*)d_in[4];
    const float* w_outs = (const float*)d_in[5];
    const float* b_outs = (const float*)d_in[6];
    const float* bog    = (const float*)d_in[7];
    const float* bob    = (const float*)d_in[8];
    const float* bom    = (const float*)d_in[9];
    const float* bov    = (const float*)d_in[10];
    const float* w_ff   = (const float*)d_in[11];
    const float* b_ff   = (const float*)d_in[12];
    const float* bfg    = (const float*)d_in[13];
    const float* bfb    = (const float*)d_in[14];
    const float* bfm    = (const float*)d_in[15];
    const float* bfv    = (const float*)d_in[16];
    const float* w_t    = (const float*)d_in[17];
    const float* b_t    = (const float*)d_in[18];
    const float* btg    = (const float*)d_in[19];
    const float* btb    = (const float*)d_in[20];
    const float* btm    = (const float*)d_in[21];
    const float* btv    = (const float*)d_in[22];

    // ws layout (f32/u32 units):
    // pb 1792 | scores 46656 | attT 27648 | wfopk 4096 | bfo 64 |
    // wffpk 2048 | bff 64 | wt2pk 6144 | bft 64 | wqkpk 2048 | y2 (u16 XTOT)
    float* pbw    = (float*)d_ws;
    float* scores = pbw + 1792;
    u32t*  attT   = (u32t*)(scores + NSUV);
    u32t*  wfopk  = attT + 27648;
    float* bfo    = (float*)(wfopk + 4096);
    u32t*  wffpk  = (u32t*)(bfo + 64);
    float* bff    = (float*)(wffpk + 2048);
    u32t*  wt2pk  = (u32t*)(bff + 64);
    float* bft    = (float*)(wt2pk + 6144);
    u32t*  wqkpk  = (u32t*)(bft + 64);
    u16t*  y2     = (u16t*)(wqkpk + 2048);

    hipMemsetAsync(scores, 0, NSUV * sizeof(float), stream);

    k_prep<<<32, 256, 0, stream>>>(w_outs, b_outs, bog, bob, bom, bov,
                                   w_ff, b_ff, bfg, bfb, bfm, bfv,
                                   w_t, b_t, btg, btb, btm, btv, w_in,
                                   wfopk, bfo, wffpk, bff, wt2pk, bft, wqkpk);
    k_pbias<<<1, 256, 0, stream>>>(w_in, b_in, pbw);
    k_scores<<<dim3(NTS, 2, NN), 256, 0, stream>>>(x, wqkpk, pbw, scores);
    k_att<<<(NN * 2 * 27 * 16 + 255) / 256, 256, 0, stream>>>(scores, alphas, att0, attT);
    k_stage1<<<dim3(NT1, NN), 256, 0, stream>>>(x, attT, wfopk, bfo, wffpk, bff, y2);
    k_stage2<<<dim3(NT2, NN), 256, 0, stream>>>(y2, wt2pk, bft, (float*)d_out);
}